// Round 9
// baseline (349.882 us; speedup 1.0000x reference)
//
#include <hip/hip_runtime.h>
#include <hip/hip_bf16.h>

using bf16x8 = __attribute__((ext_vector_type(8))) short;
using f32x4  = __attribute__((ext_vector_type(4))) float;

#define DEVI __device__ __forceinline__

DEVI unsigned short bf16r(float f)
{
    return __builtin_bit_cast(unsigned short, __float2bfloat16(f));
}

DEVI bf16x8 cvt8(const f32x4 a, const f32x4 b)
{
    bf16x8 r;
#pragma unroll
    for (int j = 0; j < 4; ++j) {
        r[j]     = (short)bf16r(a[j]);
        r[4 + j] = (short)bf16r(b[j]);
    }
    return r;
}

// ---------------- gather: x[b][:] = bf16(E[inp[b]][:]) ----------------
__global__ __launch_bounds__(256) void k_gather(const float* __restrict__ E,
                                                const int* __restrict__ inp,
                                                unsigned short* __restrict__ x)
{
    const int b = blockIdx.x;
    const long r = inp[b];
    const f32x4 v = ((const f32x4*)(E + r * 1024L))[threadIdx.x];
    ushort4 o;
    o.x = bf16r(v[0]); o.y = bf16r(v[1]); o.z = bf16r(v[2]); o.w = bf16r(v[3]);
    ((ushort4*)(x + (long)b * 1024L))[threadIdx.x] = o;
}

// ---------------- fp32 -> bf16 bulk convert (n = blocks*2048 elems) ----------------
__global__ __launch_bounds__(256) void k_cvtn(const float* __restrict__ in,
                                              unsigned short* __restrict__ out)
{
    const long i = (blockIdx.x * 256L + threadIdx.x) * 8;
    const f32x4 a = *(const f32x4*)(in + i);
    const f32x4 b = *(const f32x4*)(in + i + 4);
    *(bf16x8*)(out + i) = cvt8(a, b);
}

// =====================================================================
// GEMM core (m97 structure, ALL-bf16): 128x128 tile, BK=64, 4 waves (2x2).
// Both operands: bf16 [rows,K] staged via global_load_lds (16B granules),
// XOR swizzle slot = j ^ (row&7) pre-applied to the GLOBAL source address,
// linear LDS dest (rule #21); read side applies the same XOR.
// 2 x 16KB LDS, single-buffered, 2 barriers/tile -> ~5 blocks/CU of TLP.
// =====================================================================

DEVI bf16x8 lds_frag(const char* lds, int row, int j)
{
    return *(const bf16x8*)(lds + row * 128 + ((j ^ (row & 7)) << 4));
}

DEVI void mfma_tile(const char* sA, const char* sB, int l, int wr, int wc,
                    f32x4 (&acc)[4][4])
{
#pragma unroll
    for (int ks = 0; ks < 2; ++ks) {
        bf16x8 af[4], bq[4];
#pragma unroll
        for (int m = 0; m < 4; ++m)
            af[m] = lds_frag(sA, wr * 64 + m * 16 + (l & 15), ks * 4 + (l >> 4));
#pragma unroll
        for (int n = 0; n < 4; ++n)
            bq[n] = lds_frag(sB, wc * 64 + n * 16 + (l & 15), ks * 4 + (l >> 4));
#pragma unroll
        for (int m = 0; m < 4; ++m)
#pragma unroll
            for (int n = 0; n < 4; ++n)
                acc[m][n] = __builtin_amdgcn_mfma_f32_16x16x32_bf16(
                    af[m], bq[n], acc[m][n], 0, 0, 0);
    }
}

template <bool CLAMP>
DEVI void gemm_core(const unsigned short* __restrict__ A, long lda, long arow0,
                    const unsigned short* __restrict__ B, long ldb, long brow0,
                    long bmax, int ntiles, long kbase, int t,
                    char* sA, char* sB, f32x4 (&acc)[4][4])
{
    const int l = t & 63;
    const int wr = (t >> 7) & 1, wc = (t >> 6) & 1;

    const unsigned short* ap[4];
    const unsigned short* bp[4];
#pragma unroll
    for (int i = 0; i < 4; ++i) {
        const int g = i * 256 + t, row = g >> 3, js = g & 7;
        const long ko = kbase + (long)((js ^ (row & 7)) * 8);
        ap[i] = A + (arow0 + row) * lda + ko;
        long br = brow0 + row;
        if (CLAMP) br = (br < bmax) ? br : (bmax - 1);
        bp[i] = B + br * ldb + ko;
    }

    for (int ti = 0; ti < ntiles; ++ti) {
        __syncthreads();                       // WAR: prev tile fully consumed
#pragma unroll
        for (int i = 0; i < 4; ++i) {
            __builtin_amdgcn_global_load_lds(
                (const __attribute__((address_space(1))) void*)(ap[i]),
                (__attribute__((address_space(3))) void*)(sA + (i * 256 + t) * 16),
                16, 0, 0);
            ap[i] += 64;
        }
#pragma unroll
        for (int i = 0; i < 4; ++i) {
            __builtin_amdgcn_global_load_lds(
                (const __attribute__((address_space(1))) void*)(bp[i]),
                (__attribute__((address_space(3))) void*)(sB + (i * 256 + t) * 16),
                16, 0, 0);
            bp[i] += 64;
        }
        __syncthreads();                       // RAW: vmcnt drained, tile visible
        mfma_tile(sA, sB, l, wr, wc, acc);
    }
}

// ---------------- gates GEMM (+ fused Wd fp32->bf16 conversion) ----------------
// Blocks [0,768): gates chunk z of (x@Wxb^T | h0@Whb^T), XCD-chunked swizzle.
// Blocks [768,2032): grid-stride convert Wd (102,926,336 fp32) -> Wdb bf16.
__global__ __launch_bounds__(256, 3) void k_gates_cvt(
    const unsigned short* __restrict__ xb, const unsigned short* __restrict__ Wxb,
    const unsigned short* __restrict__ h0b, const unsigned short* __restrict__ Whb,
    float* __restrict__ g0, float* __restrict__ g1, float* __restrict__ g2,
    const float* __restrict__ Wd, unsigned short* __restrict__ Wdb)
{
    __shared__ __align__(16) char sA[16384];
    __shared__ __align__(16) char sB[16384];
    const int t = threadIdx.x;
    const int bid = blockIdx.x;

    if (bid >= 768) {                          // -------- Wd conversion path
        const long stride = 1264L * 256 * 8;
        long i = ((bid - 768) * 256L + t) * 8;
        for (; i < 102926336L; i += stride) {
            const f32x4 a = *(const f32x4*)(Wd + i);
            const f32x4 b = *(const f32x4*)(Wd + i + 4);
            *(bf16x8*)(Wdb + i) = cvt8(a, b);
        }
        return;
    }

    // -------- gates GEMM path (768 blocks, XCD-chunked: q=96, r=0)
    const int xcd = bid & 7, slot = bid >> 3;
    const int L = xcd * 96 + slot;
    const int mtile = L & 3;
    const int rest = L >> 2;
    const int ntile = rest & 63;
    const int z = rest >> 6;

    const unsigned short *A, *B; long lda, ldb, kbase; float* C;
    if (z == 0)      { A = xb;  lda = 1024; B = Wxb; ldb = 1024; kbase = 0;    C = g0; }
    else if (z == 1) { A = h0b; lda = 2048; B = Whb; ldb = 2048; kbase = 0;    C = g1; }
    else             { A = h0b; lda = 2048; B = Whb; ldb = 2048; kbase = 1024; C = g2; }

    f32x4 acc[4][4] = {};
    gemm_core<false>(A, lda, (long)mtile * 128, B, ldb, (long)ntile * 128,
                     1L << 40, 16, kbase, t, sA, sB, acc);

    const int l = t & 63;
    const int wr = (t >> 7) & 1, wc = (t >> 6) & 1;
    const int lc = l & 15, r4 = (l >> 4) * 4;
#pragma unroll
    for (int n = 0; n < 4; ++n) {
        const long col = (long)ntile * 128 + wc * 64 + n * 16 + lc;
#pragma unroll
        for (int m = 0; m < 4; ++m) {
            const long row = (long)mtile * 128 + wr * 64 + m * 16 + r4;
#pragma unroll
            for (int r = 0; r < 4; ++r)
                C[(row + r) * 8192 + col] = acc[m][n][r];
        }
    }
}

// ---------------- decoder GEMM: out = hx @ Wdb^T + bd ----------------
// 1572 blocks: bijective XCD-chunk swizzle (q=196, r=4, m204 formula).
__global__ __launch_bounds__(256, 3) void k_dec(
    const unsigned short* __restrict__ hxb, const unsigned short* __restrict__ Wdb,
    const float* __restrict__ bd, float* __restrict__ out)
{
    __shared__ __align__(16) char sA[16384];
    __shared__ __align__(16) char sB[16384];
    const int t = threadIdx.x;
    const int bid = blockIdx.x;
    const int xcd = bid & 7, slot = bid >> 3;
    const int L = xcd * 196 + (xcd < 4 ? xcd : 4) + slot;
    const int mtile = L & 3;
    const int ntile = L >> 2;                  // 0..392
    const long N = 50257;

    f32x4 acc[4][4] = {};
    gemm_core<true>(hxb, 2048, (long)mtile * 128, Wdb, 2048, (long)ntile * 128,
                    N, 32, 0, t, sA, sB, acc);

    const int l = t & 63;
    const int wr = (t >> 7) & 1, wc = (t >> 6) & 1;
    const int lc = l & 15, r4 = (l >> 4) * 4;
#pragma unroll
    for (int n = 0; n < 4; ++n) {
        const long col = (long)ntile * 128 + wc * 64 + n * 16 + lc;
        if (col >= N) continue;
        const float bias = bd[col];
#pragma unroll
        for (int m = 0; m < 4; ++m) {
            const long row = (long)mtile * 128 + wr * 64 + m * 16 + r4;
#pragma unroll
            for (int r = 0; r < 4; ++r)
                out[(row + r) * N + col] = acc[m][n][r] + bias;
        }
    }
}

// ---------------- elementwise LSTM cell: combine 3 partials + biases ----------------
__global__ __launch_bounds__(256) void k_lstm(
    const float* __restrict__ g0, const float* __restrict__ g1,
    const float* __restrict__ g2, const float* __restrict__ bx,
    const float* __restrict__ bh, const float* __restrict__ c0,
    float* __restrict__ hx, float* __restrict__ cx,
    unsigned short* __restrict__ hxb)
{
    const int i = blockIdx.x * 256 + threadIdx.x;
    const int b = i >> 9;
    const int hc = (i & 511) << 2;
    const long base = (long)b * 8192;

    f32x4 g[4];
#pragma unroll
    for (int gi = 0; gi < 4; ++gi) {
        const long off = base + gi * 2048 + hc;
        const int boff = gi * 2048 + hc;
        g[gi] = *(const f32x4*)(g0 + off);
        g[gi] += *(const f32x4*)(g1 + off);
        g[gi] += *(const f32x4*)(g2 + off);
        g[gi] += *(const f32x4*)(bx + boff);
        g[gi] += *(const f32x4*)(bh + boff);
    }
    const f32x4 c0v = *(const f32x4*)(c0 + (long)b * 2048 + hc);

    f32x4 cv, hv;
    ushort4 hb;
#pragma unroll
    for (int j = 0; j < 4; ++j) {
        const float fg = 1.f / (1.f + __expf(-g[0][j]));
        const float ig = 1.f / (1.f + __expf(-g[1][j]));
        const float og = 1.f / (1.f + __expf(-g[2][j]));
        const float e2 = __expf(2.f * g[3][j]);
        const float ct = 1.f - 2.f / (e2 + 1.f);
        const float c  = fg * c0v[j] + ig * ct;
        const float e2c = __expf(2.f * c);
        const float th  = 1.f - 2.f / (e2c + 1.f);
        cv[j] = c;
        hv[j] = og * th;
    }
    hb.x = bf16r(hv[0]); hb.y = bf16r(hv[1]); hb.z = bf16r(hv[2]); hb.w = bf16r(hv[3]);

    const long o = (long)b * 2048 + hc;
    *(f32x4*)(cx + o) = cv;
    *(f32x4*)(hx + o) = hv;
    *(ushort4*)(hxb + o) = hb;
}

// ---------------- launch ----------------
extern "C" void kernel_launch(void* const* d_in, const int* in_sizes, int n_in,
                              void* d_out, int out_size, void* d_ws, size_t ws_size,
                              hipStream_t stream)
{
    const int*   inp = (const int*)d_in[0];
    const float* h0  = (const float*)d_in[1];
    const float* c0  = (const float*)d_in[2];
    const float* E   = (const float*)d_in[3];
    const float* Wx  = (const float*)d_in[4];   // (8192,1024)
    const float* bx  = (const float*)d_in[5];
    const float* Wh  = (const float*)d_in[6];   // (8192,2048)
    const float* bh  = (const float*)d_in[7];
    const float* Wd  = (const float*)d_in[8];   // (50257,2048)
    const float* bd  = (const float*)d_in[9];

    float* out = (float*)d_out;                 // [512][50257]
    float* hx  = out + 512L * 50257L;           // [512][2048]
    float* cx  = hx + 512L * 2048L;

    // Scratch in the out region (consumed before k_dec overwrites out):
    //   xb @ 0 (0.5MB), g0 @ 1M floats, g1 @ 5M, g2 @ 9M, h0b @ 13M floats.
    unsigned short* xb  = (unsigned short*)out;
    float* g0 = out + (1L << 20);
    float* g1 = out + (5L << 20);
    float* g2 = out + (9L << 20);
    unsigned short* h0b = (unsigned short*)(out + (13L << 20));
    // d_ws layout (ws ~1.5GB): hxb @0 (2MB), Wdb @4MB (206MB),
    // Wxb @216MB (16MB), Whb @236MB (32MB).
    char* ws = (char*)d_ws;
    unsigned short* hxb = (unsigned short*)ws;
    unsigned short* Wdb = (unsigned short*)(ws + (4L << 20));
    unsigned short* Wxb = (unsigned short*)(ws + (216L << 20));
    unsigned short* Whb = (unsigned short*)(ws + (236L << 20));

    k_gather<<<512, 256, 0, stream>>>(E, inp, xb);
    k_cvtn<<<512, 256, 0, stream>>>(h0, h0b);        // 1,048,576 elems
    k_cvtn<<<4096, 256, 0, stream>>>(Wx, Wxb);       // 8,388,608 elems
    k_cvtn<<<8192, 256, 0, stream>>>(Wh, Whb);       // 16,777,216 elems

    k_gates_cvt<<<2032, 256, 0, stream>>>(xb, Wxb, h0b, Whb, g0, g1, g2, Wd, Wdb);

    k_lstm<<<1024, 256, 0, stream>>>(g0, g1, g2, bx, bh, c0, hx, cx, hxb);

    k_dec<<<1572, 256, 0, stream>>>(hxb, Wdb, bd, out);
}

// Round 11
// 284.834 us; speedup vs baseline: 1.2284x; 1.2284x over previous
//
#include <hip/hip_runtime.h>
#include <hip/hip_bf16.h>

using bf16x8 = __attribute__((ext_vector_type(8))) short;
using f32x4  = __attribute__((ext_vector_type(4))) float;

#define DEVI __device__ __forceinline__

DEVI unsigned short bf16r(float f)
{
    return __builtin_bit_cast(unsigned short, __float2bfloat16(f));
}

DEVI bf16x8 cvt8(const f32x4 a, const f32x4 b)
{
    bf16x8 r;
#pragma unroll
    for (int j = 0; j < 4; ++j) {
        r[j]     = (short)bf16r(a[j]);
        r[4 + j] = (short)bf16r(b[j]);
    }
    return r;
}

// ---------------- gather: x[b][:] = bf16(E[inp[b]][:]) ----------------
__global__ __launch_bounds__(256) void k_gather(const float* __restrict__ E,
                                                const int* __restrict__ inp,
                                                unsigned short* __restrict__ x)
{
    const int b = blockIdx.x;
    const long r = inp[b];
    const f32x4 v = ((const f32x4*)(E + r * 1024L))[threadIdx.x];
    ushort4 o;
    o.x = bf16r(v[0]); o.y = bf16r(v[1]); o.z = bf16r(v[2]); o.w = bf16r(v[3]);
    ((ushort4*)(x + (long)b * 1024L))[threadIdx.x] = o;
}

// ---------------- fp32 -> bf16 bulk convert ----------------
__global__ __launch_bounds__(256) void k_cvtn(const float* __restrict__ in,
                                              unsigned short* __restrict__ out)
{
    const long i = (blockIdx.x * 256L + threadIdx.x) * 8;
    const f32x4 a = *(const f32x4*)(in + i);
    const f32x4 b = *(const f32x4*)(in + i + 4);
    *(bf16x8*)(out + i) = cvt8(a, b);
}

// =====================================================================
// Deep-pipelined GEMM core: BM=256 x BN=128, BK=64, 512 threads (8 waves,
// 4M x 2N, per-wave 64x64 = acc[4][4], 32 MFMA/K-tile).
//   A: bf16 [M,K]  -> 4 bf16x8 reg loads/thread -> ds_write (swizzled)
//   B: fp32 [N,K]  -> 4 f32x4 reg loads/thread  -> cvt8 -> ds_write (swizzled)
// Double-buffered LDS (sA 2x32KB, sB 2x16KB = 96KB dynamic, 1 block/CU).
// Counted pipeline: 2 reg-sets leapfrog; s_waitcnt vmcnt(8) keeps the next
// K-tile's 8 loads IN FLIGHT across the single per-K-tile barrier (T4).
// Swizzle: slot = j ^ (row&7), same XOR on ds_write and ds_read.
// =====================================================================

DEVI bf16x8 lds_frag(const char* lds, int row, int j)
{
    return *(const bf16x8*)(lds + row * 128 + ((j ^ (row & 7)) << 4));
}

DEVI void mfma_tile8(const char* sA, const char* sB, int l, int wr, int wc,
                     f32x4 (&acc)[4][4])
{
#pragma unroll
    for (int ks = 0; ks < 2; ++ks) {
        bf16x8 af[4], bq[4];
#pragma unroll
        for (int m = 0; m < 4; ++m)
            af[m] = lds_frag(sA, wr * 64 + m * 16 + (l & 15), ks * 4 + (l >> 4));
#pragma unroll
        for (int n = 0; n < 4; ++n)
            bq[n] = lds_frag(sB, wc * 64 + n * 16 + (l & 15), ks * 4 + (l >> 4));
#pragma unroll
        for (int m = 0; m < 4; ++m)
#pragma unroll
            for (int n = 0; n < 4; ++n)
                acc[m][n] = __builtin_amdgcn_mfma_f32_16x16x32_bf16(
                    af[m], bq[n], acc[m][n], 0, 0, 0);
    }
}

template <bool CLAMP>
DEVI void gemm_core8(const unsigned short* __restrict__ A, long lda, long arow0,
                     const float* __restrict__ B, long ldb, long brow0, long bmax,
                     int nt, long kbase, int t, char* lds, f32x4 (&acc)[4][4])
{
    char* sA0 = lds;
    char* sA1 = lds + 32768;
    char* sB0 = lds + 65536;
    char* sB1 = lds + 81920;
    const int l = t & 63, w = t >> 6, wr = w >> 1, wc = w & 1;

    // A: 256 rows x 8 granules = 2048 -> 4/thread. B: 128 rows x 8 (8-elem)
    // granules = 1024 -> 2/thread (2 f32x4 each).
    const unsigned short* ap[4];
    int aswz[4];
#pragma unroll
    for (int i = 0; i < 4; ++i) {
        const int g = i * 512 + t, row = g >> 3, j = g & 7;
        ap[i] = A + (arow0 + row) * lda + kbase + j * 8;
        aswz[i] = row * 128 + ((j ^ (row & 7)) << 4);
    }
    const float* bp[2];
    int bswz[2];
#pragma unroll
    for (int i = 0; i < 2; ++i) {
        const int g = i * 512 + t, row = g >> 3, j = g & 7;
        long br = brow0 + row;
        if (CLAMP) br = (br < bmax) ? br : (bmax - 1);
        bp[i] = B + br * ldb + kbase + j * 8;
        bswz[i] = row * 128 + ((j ^ (row & 7)) << 4);
    }

    bf16x8 ra0[4], ra1[4];
    f32x4 rb0[4], rb1[4];

#define LOADR(as, bs)                                                          \
    do {                                                                       \
        _Pragma("unroll") for (int i = 0; i < 4; ++i) {                        \
            as[i] = *(const bf16x8*)ap[i];                                     \
            ap[i] += 64;                                                       \
        }                                                                      \
        _Pragma("unroll") for (int i = 0; i < 2; ++i) {                        \
            bs[2 * i]     = *(const f32x4*)bp[i];                              \
            bs[2 * i + 1] = *(const f32x4*)(bp[i] + 4);                        \
            bp[i] += 64;                                                       \
        }                                                                      \
    } while (0)
#define WRLDS(sa, sb, as, bs)                                                  \
    do {                                                                       \
        _Pragma("unroll") for (int i = 0; i < 4; ++i)                          \
            *(bf16x8*)((sa) + aswz[i]) = as[i];                                \
        _Pragma("unroll") for (int i = 0; i < 2; ++i)                          \
            *(bf16x8*)((sb) + bswz[i]) = cvt8(bs[2 * i], bs[2 * i + 1]);       \
    } while (0)
#define WAITV8  asm volatile("s_waitcnt vmcnt(8)" ::: "memory")
#define WAITV0  asm volatile("s_waitcnt vmcnt(0)" ::: "memory")
#define WAITL0  asm volatile("s_waitcnt lgkmcnt(0)" ::: "memory")
#define BARRIER __builtin_amdgcn_s_barrier()

    // Prologue: K-tiles 0,1 in regs; write 0; issue 2.   [16 -> 8 -> 16 inflight]
    LOADR(ra0, rb0);                 // set0 <- kt 0
    LOADR(ra1, rb1);                 // set1 <- kt 1
    WAITV8;                          // set0 ready (set1 in flight)
    WRLDS(sA0, sB0, ra0, rb0);
    LOADR(ra0, rb0);                 // set0 <- kt 2 (in flight)
    WAITL0; BARRIER;                 // buf0 visible

    for (int kt = 0; kt < nt; kt += 2) {
        // EVEN: write kt+1 -> buf1 (from set1), compute kt (buf0).
        if (kt + 2 < nt) WAITV8; else WAITV0;       // set1 (kt+1) ready
        WRLDS(sA1, sB1, ra1, rb1);
        if (kt + 3 < nt) LOADR(ra1, rb1);           // set1 <- kt+3
        mfma_tile8(sA0, sB0, l, wr, wc, acc);
        WAITL0; BARRIER;                            // buf1 visible; buf0 free
        // ODD: write kt+2 -> buf0 (from set0), compute kt+1 (buf1).
        if (kt + 2 < nt) {
            if (kt + 3 < nt) WAITV8; else WAITV0;   // set0 (kt+2) ready
            WRLDS(sA0, sB0, ra0, rb0);
            if (kt + 4 < nt) LOADR(ra0, rb0);       // set0 <- kt+4
        }
        mfma_tile8(sA1, sB1, l, wr, wc, acc);
        WAITL0; BARRIER;
    }
#undef LOADR
#undef WRLDS
#undef WAITV8
#undef WAITV0
#undef WAITL0
#undef BARRIER
}

// ---------------- gates GEMM: chunk z of (x@Wx^T | h0@Wh^T) ----------------
// 384 blocks (512 thr): XCD chunk q=48,r=0. L -> z = L>>7, mtile = L&1,
// ntile = (L>>1)&63  (mtile-adjacent => B-strip shared on one XCD's L2).
__global__ __launch_bounds__(512, 2) void k_gates(
    const unsigned short* __restrict__ xb, const float* __restrict__ Wx,
    const unsigned short* __restrict__ h0b, const float* __restrict__ Wh,
    float* __restrict__ g0, float* __restrict__ g1, float* __restrict__ g2)
{
    extern __shared__ __align__(16) char lds[];
    const int t = threadIdx.x;
    const int bid = blockIdx.x;
    const int xcd = bid & 7, slot = bid >> 3;
    const int L = xcd * 48 + slot;
    const int z = L >> 7;
    const int mtile = L & 1;
    const int ntile = (L >> 1) & 63;

    const unsigned short* A; const float* B; long lda, ldb, kbase; float* C; int nt;
    if (z == 0)      { A = xb;  lda = 1024; B = Wx; ldb = 1024; kbase = 0;    C = g0; nt = 16; }
    else if (z == 1) { A = h0b; lda = 2048; B = Wh; ldb = 2048; kbase = 0;    C = g1; nt = 16; }
    else             { A = h0b; lda = 2048; B = Wh; ldb = 2048; kbase = 1024; C = g2; nt = 16; }

    f32x4 acc[4][4] = {};
    gemm_core8<false>(A, lda, (long)mtile * 256, B, ldb, (long)ntile * 128,
                      1L << 40, nt, kbase, t, lds, acc);

    const int l = t & 63, w = t >> 6, wr = w >> 1, wc = w & 1;
    const int lc = l & 15, r4 = (l >> 4) * 4;
#pragma unroll
    for (int n = 0; n < 4; ++n) {
        const long col = (long)ntile * 128 + wc * 64 + n * 16 + lc;
#pragma unroll
        for (int m = 0; m < 4; ++m) {
            const long row = (long)mtile * 256 + wr * 64 + m * 16 + r4;
#pragma unroll
            for (int r = 0; r < 4; ++r)
                C[(row + r) * 8192 + col] = acc[m][n][r];
        }
    }
}

// ---------------- decoder GEMM: out = hx @ Wd^T + bd  (fp32 Wd direct) -------
// 786 blocks (512 thr): bijective XCD chunk q=98, r=2. mtile = L&1,
// ntile = L>>1 (0..392).
__global__ __launch_bounds__(512, 2) void k_dec(
    const unsigned short* __restrict__ hxb, const float* __restrict__ Wd,
    const float* __restrict__ bd, float* __restrict__ out)
{
    extern __shared__ __align__(16) char lds[];
    const int t = threadIdx.x;
    const int bid = blockIdx.x;
    const int xcd = bid & 7, slot = bid >> 3;
    const int L = (xcd < 2) ? (xcd * 99 + slot) : (198 + (xcd - 2) * 98 + slot);
    const int mtile = L & 1;
    const int ntile = L >> 1;
    const long N = 50257;

    f32x4 acc[4][4] = {};
    gemm_core8<true>(hxb, 2048, (long)mtile * 256, Wd, 2048, (long)ntile * 128,
                     N, 32, 0, t, lds, acc);

    const int l = t & 63, w = t >> 6, wr = w >> 1, wc = w & 1;
    const int lc = l & 15, r4 = (l >> 4) * 4;
#pragma unroll
    for (int n = 0; n < 4; ++n) {
        const long col = (long)ntile * 128 + wc * 64 + n * 16 + lc;
        if (col >= N) continue;
        const float bias = bd[col];
#pragma unroll
        for (int m = 0; m < 4; ++m) {
            const long row = (long)mtile * 256 + wr * 64 + m * 16 + r4;
#pragma unroll
            for (int r = 0; r < 4; ++r)
                out[(row + r) * N + col] = acc[m][n][r] + bias;
        }
    }
}

// ---------------- elementwise LSTM cell: combine 3 partials + biases ----------------
__global__ __launch_bounds__(256) void k_lstm(
    const float* __restrict__ g0, const float* __restrict__ g1,
    const float* __restrict__ g2, const float* __restrict__ bx,
    const float* __restrict__ bh, const float* __restrict__ c0,
    float* __restrict__ hx, float* __restrict__ cx,
    unsigned short* __restrict__ hxb)
{
    const int i = blockIdx.x * 256 + threadIdx.x;
    const int b = i >> 9;
    const int hc = (i & 511) << 2;
    const long base = (long)b * 8192;

    f32x4 g[4];
#pragma unroll
    for (int gi = 0; gi < 4; ++gi) {
        const long off = base + gi * 2048 + hc;
        const int boff = gi * 2048 + hc;
        g[gi] = *(const f32x4*)(g0 + off);
        g[gi] += *(const f32x4*)(g1 + off);
        g[gi] += *(const f32x4*)(g2 + off);
        g[gi] += *(const f32x4*)(bx + boff);
        g[gi] += *(const f32x4*)(bh + boff);
    }
    const f32x4 c0v = *(const f32x4*)(c0 + (long)b * 2048 + hc);

    f32x4 cv, hv;
    ushort4 hb;
#pragma unroll
    for (int j = 0; j < 4; ++j) {
        const float fg = 1.f / (1.f + __expf(-g[0][j]));
        const float ig = 1.f / (1.f + __expf(-g[1][j]));
        const float og = 1.f / (1.f + __expf(-g[2][j]));
        const float e2 = __expf(2.f * g[3][j]);
        const float ct = 1.f - 2.f / (e2 + 1.f);
        const float c  = fg * c0v[j] + ig * ct;
        const float e2c = __expf(2.f * c);
        const float th  = 1.f - 2.f / (e2c + 1.f);
        cv[j] = c;
        hv[j] = og * th;
    }
    hb.x = bf16r(hv[0]); hb.y = bf16r(hv[1]); hb.z = bf16r(hv[2]); hb.w = bf16r(hv[3]);

    const long o = (long)b * 2048 + hc;
    *(f32x4*)(cx + o) = cv;
    *(f32x4*)(hx + o) = hv;
    *(ushort4*)(hxb + o) = hb;
}

// ---------------- launch ----------------
extern "C" void kernel_launch(void* const* d_in, const int* in_sizes, int n_in,
                              void* d_out, int out_size, void* d_ws, size_t ws_size,
                              hipStream_t stream)
{
    const int*   inp = (const int*)d_in[0];
    const float* h0  = (const float*)d_in[1];
    const float* c0  = (const float*)d_in[2];
    const float* E   = (const float*)d_in[3];
    const float* Wx  = (const float*)d_in[4];   // (8192,1024)
    const float* bx  = (const float*)d_in[5];
    const float* Wh  = (const float*)d_in[6];   // (8192,2048)
    const float* bh  = (const float*)d_in[7];
    const float* Wd  = (const float*)d_in[8];   // (50257,2048)
    const float* bd  = (const float*)d_in[9];

    float* out = (float*)d_out;                 // [512][50257]
    float* hx  = out + 512L * 50257L;           // [512][2048]
    float* cx  = hx + 512L * 2048L;

    // Scratch in the out region (all consumed before k_dec overwrites out):
    //   xb @ 0 (0.5MB), g0 @ 1M floats, g1 @ 5M, g2 @ 9M, h0b @ 13M floats.
    unsigned short* xb  = (unsigned short*)out;
    float* g0 = out + (1L << 20);
    float* g1 = out + (5L << 20);
    float* g2 = out + (9L << 20);
    unsigned short* h0b = (unsigned short*)(out + (13L << 20));
    // hxb read during k_dec (which writes out) -> lives in d_ws.
    unsigned short* hxb = (unsigned short*)d_ws;

    k_gather<<<512, 256, 0, stream>>>(E, inp, xb);
    k_cvtn<<<512, 256, 0, stream>>>(h0, h0b);

    k_gates<<<384, 512, 98304, stream>>>(xb, Wx, h0b, Wh, g0, g1, g2);

    k_lstm<<<1024, 256, 0, stream>>>(g0, g1, g2, bx, bh, c0, hx, cx, hxb);

    k_dec<<<786, 512, 98304, stream>>>(hxb, Wd, bd, out);
}